// Round 7
// baseline (139.535 us; speedup 1.0000x reference)
//
#include <hip/hip_runtime.h>

// VQ: x (16,64,64,64) f32, codebook e (64,1024) f32. N=65536, D=64, K=1024.
//
// R7 = R6's certified MFMA scheme, restructured for occupancy + bandwidth:
//  - 2 dispatches: vq_prep (frags + eT + c2 + norms fused), vq_main
//    (scores + epilogue + BLOCK-LOCAL exact fallback; no global worklist).
//  - vq_main: 1024 blocks x 256 (64 pos/block, 1 M-tile/wave) -> 4 blocks/CU.
//    B-frags double-buffered in LDS via global_load_lds(16B), shared by all
//    4 waves (cache traffic halved vs R6, prefetched 1 tile ahead).
//  - epilogue: winning rows copied fp32 from eT (contiguous 256 B reads) into
//    stride-65 LDS, then strided-coalesced store. No 64-way column gather.
// Numerics identical to R6 (passed, absmax 0): same split-bf16 frags, same
// MFMA order, MARGIN certify, np-bit-exact fallback chain + first-index ties.

#define D 64
#define K 1024
#define NPOS 65536
#define HW 4096
#define XSTRIDE 262144  // D*HW
#define MARGIN 1.0e-3f

typedef float vfloat4 __attribute__((ext_vector_type(4)));
typedef short short8  __attribute__((ext_vector_type(8)));

static __device__ __forceinline__ unsigned short bf16_rne(float f) {
    unsigned u = __float_as_uint(f);
    u += 0x7FFFu + ((u >> 16) & 1u);
    return (unsigned short)(u >> 16);
}
static __device__ __forceinline__ float bf16_to_f32(unsigned short h) {
    return __uint_as_float(((unsigned)h) << 16);
}

// ---- fused prep: blocks 0..63 frag+eT, 64..67 c2, 68..323 norms ----------
__global__ __launch_bounds__(256)
void vq_prep(const float* __restrict__ e, const float* __restrict__ x,
             unsigned short* __restrict__ ebf, float* __restrict__ eT,
             float* __restrict__ c2, float* __restrict__ A) {
    const int blk = blockIdx.x;
    const int t = threadIdx.x;
    if (blk < 64) {
        const int tile = blk;
        const int n = t & 15, dg = t >> 4;
#pragma unroll
        for (int i = 0; i < 4; ++i) {
            const int d = dg * 4 + i;
            const int k = tile * 16 + n;
            const float v = e[d * K + k];
            eT[k * 64 + d] = v;                       // fp32 row copy
            const unsigned short hh = bf16_rne(v);
            const float rem = v - bf16_to_f32(hh);    // exact
            const unsigned short hl = bf16_rne(rem);
            const int s = d >> 5, q = (d >> 3) & 3, j = d & 7;
            const int lanei = q * 16 + n;
            ebf[(((tile * 2 + s) * 2 + 0) * 64 + lanei) * 8 + j] = hh;
            ebf[(((tile * 2 + s) * 2 + 1) * 64 + lanei) * 8 + j] = hl;
        }
    } else if (blk < 68) {
        const int k = (blk - 64) * 256 + t;
        float s = 0.f;
#pragma unroll
        for (int d = 0; d < D; ++d) {                 // np axis-0: sequential
            const float v = e[d * K + k];
            s = s + __fmul_rn(v, v);
        }
        c2[k] = s;
    } else {
        const int pos = (blk - 68) * 256 + t;
        const int b = pos >> 12, sp = pos & (HW - 1);
        const float* xp = x + (size_t)b * XSTRIDE + sp;
        float xv[D];
#pragma unroll
        for (int d = 0; d < D; ++d) xv[d] = xp[(size_t)d * HW];
        float r[8];                                   // np pairwise-8, n=64
#pragma unroll
        for (int i = 0; i < 8; ++i) r[i] = __fmul_rn(xv[i], xv[i]);
#pragma unroll
        for (int j = 1; j < 8; ++j)
#pragma unroll
            for (int i = 0; i < 8; ++i)
                r[i] = r[i] + __fmul_rn(xv[8 * j + i], xv[8 * j + i]);
        A[pos] = ((r[0] + r[1]) + (r[2] + r[3])) + ((r[4] + r[5]) + (r[6] + r[7]));
    }
}

// ---- main: 1024 blocks x 256; block = 64 positions; wave = 1 M-tile ------
__global__ __launch_bounds__(256, 4)
void vq_main(const float* __restrict__ x, const float* __restrict__ e,
             const unsigned short* __restrict__ ebf,
             const float* __restrict__ eT,
             const float* __restrict__ c2g, const float* __restrict__ A,
             float* __restrict__ out) {
    __shared__ short8 fb[2][2][2][64];   // [buf][ktile][split][lane], 8 KB
    __shared__ float  c2_lds[K];         // 4 KB
    __shared__ float  q_lds[64][65];     // quantized rows, pad 65: bank-free
    __shared__ int    bk_lds[64];
    __shared__ int    amb_cnt;
    __shared__ int    amb_list[64];
    __shared__ float  rs[256];
    __shared__ int    rk[256];

    const int t    = threadIdx.x;
    const int lane = t & 63;
    const int w    = t >> 6;
    const int n    = lane & 15;          // B col (code-in-tile) / A row m
    const int q    = lane >> 4;          // k-quad / C row group
    const int p0   = blockIdx.x * 64;
    const int b    = p0 >> 12;
    const int sp0  = p0 & (HW - 1);

    if (t == 0) amb_cnt = 0;
    *(vfloat4*)(&c2_lds[t * 4]) = *(const vfloat4*)(c2g + t * 4);

    // ---- A-frags (registers): split-bf16 of this wave's 16 positions
    short8 ah[2], al[2];
    float An[4];
    {
        const int spc = sp0 + w * 16 + n;
#pragma unroll
        for (int s = 0; s < 2; ++s) {
            short8 fh, fl_;
#pragma unroll
            for (int j = 0; j < 8; ++j) {
                const int d = s * 32 + q * 8 + j;     // A[m=n][k=q*8+j]
                const float v = x[(size_t)b * XSTRIDE + (size_t)d * HW + spc];
                const unsigned short h = bf16_rne(v);
                fh[j] = (short)h;
                fl_[j] = (short)bf16_rne(v - bf16_to_f32(h));
            }
            ah[s] = fh; al[s] = fl_;
        }
        const vfloat4 Av = *(const vfloat4*)(A + p0 + w * 16 + q * 4);
#pragma unroll
        for (int r = 0; r < 4; ++r) An[r] = Av[r];
    }

    // ---- stage tile 0 into fb[0] (256 thr x 16 B = 4 KB, one tile)
    {
        const char* src = (const char*)ebf + (size_t)0 * 4096 + t * 16;
        char* dst = (char*)(&fb[0][0][0][0]) + t * 16;
        __builtin_amdgcn_global_load_lds(
            (const __attribute__((address_space(1))) unsigned int*)src,
            (__attribute__((address_space(3))) unsigned int*)dst, 16, 0, 0);
    }
    __syncthreads();

    float s1v[4], s2v[4]; int t1v[4];
#pragma unroll
    for (int r = 0; r < 4; ++r) { s1v[r] = 3.4e38f; s2v[r] = 3.4e38f; t1v[r] = 0; }

    for (int tile = 0; tile < 64; ++tile) {
        const int buf = tile & 1;
        if (tile < 63) {                 // prefetch next tile into other buf
            const char* src = (const char*)ebf + (size_t)(tile + 1) * 4096 + t * 16;
            char* dst = (char*)(&fb[buf ^ 1][0][0][0]) + t * 16;
            __builtin_amdgcn_global_load_lds(
                (const __attribute__((address_space(1))) unsigned int*)src,
                (__attribute__((address_space(3))) unsigned int*)dst, 16, 0, 0);
        }
        const short8 bh0 = fb[buf][0][0][lane];       // ds_read_b128, no-conf
        const short8 bl0 = fb[buf][0][1][lane];
        const short8 bh1 = fb[buf][1][0][lane];
        const short8 bl1 = fb[buf][1][1][lane];
        const float c2v = c2_lds[tile * 16 + n];

        vfloat4 acc = {0.f, 0.f, 0.f, 0.f};           // same order as R6
        acc = __builtin_amdgcn_mfma_f32_16x16x32_bf16(ah[0], bh0, acc, 0, 0, 0);
        acc = __builtin_amdgcn_mfma_f32_16x16x32_bf16(ah[1], bh1, acc, 0, 0, 0);
        acc = __builtin_amdgcn_mfma_f32_16x16x32_bf16(al[0], bh0, acc, 0, 0, 0);
        acc = __builtin_amdgcn_mfma_f32_16x16x32_bf16(al[1], bh1, acc, 0, 0, 0);
        acc = __builtin_amdgcn_mfma_f32_16x16x32_bf16(ah[0], bl0, acc, 0, 0, 0);
        acc = __builtin_amdgcn_mfma_f32_16x16x32_bf16(ah[1], bl1, acc, 0, 0, 0);

#pragma unroll
        for (int r = 0; r < 4; ++r) {    // top-2, invariant s1<=s2:
            const float sc = __builtin_fmaf(-2.f, acc[r], An[r]) + c2v;
            const bool lt1 = sc < s1v[r];
            s2v[r] = fminf(fmaxf(sc, s1v[r]), s2v[r]);  // med3 clamp form
            s1v[r] = fminf(s1v[r], sc);
            t1v[r] = lt1 ? tile : t1v[r];
        }
        __syncthreads();                 // buf^1 staged; all reads of buf done
    }

    // ---- merge top-2 across the 16 code-columns (butterfly over n)
#pragma unroll
    for (int r = 0; r < 4; ++r) {
        float a1 = s1v[r], a2 = s2v[r];
        int ak = t1v[r] * 16 + n;
#pragma unroll
        for (int m = 1; m < 16; m <<= 1) {
            const float o1 = __shfl_xor(a1, m, 64);
            const float o2 = __shfl_xor(a2, m, 64);
            const int   ok = __shfl_xor(ak, m, 64);
            const bool take = (o1 < a1) || (o1 == a1 && ok < ak);
            const float loser = take ? a1 : o1;
            a1 = take ? o1 : a1;
            ak = take ? ok : ak;
            a2 = fminf(fminf(a2, o2), loser);
        }
        if (n == 0) {
            const int pl = w * 16 + q * 4 + r;
            bk_lds[pl] = ak;
            if (a2 - a1 <= MARGIN) {     // uncertified -> block-local redo
                const int idx = atomicAdd(&amb_cnt, 1);
                amb_list[idx] = pl;
            }
        }
    }
    __syncthreads();

    // ---- epilogue: stage winning fp32 rows (contiguous reads) into LDS
    {
        const int pl = t >> 2, seg = t & 3;
        const float* er = eT + (size_t)bk_lds[pl] * 64 + seg * 16;
#pragma unroll
        for (int i = 0; i < 4; ++i)
            *(vfloat4*)(&q_lds[pl][seg * 16 + i * 4]) = *(const vfloat4*)(er + i * 4);
    }
    __syncthreads();
    {
        const int pl = t & 63, grp = t >> 6;
        const int sp = sp0 + pl;
        const float* xb = x + (size_t)b * XSTRIDE + sp;
        float* ob = out + (size_t)b * XSTRIDE + sp;
#pragma unroll
        for (int i = 0; i < 16; ++i) {
            const int c = grp * 16 + i;
            const float xq = xb[(size_t)c * HW];      // coalesced 64 lanes
            const float qv = q_lds[pl][c];            // pad-65: conflict-free
            ob[(size_t)c * HW] = xq + (qv - xq);      // np STE
        }
    }

    // ---- block-local exact fallback (np-bit-exact scan, usually 0 iters)
    __syncthreads();
    const int na = amb_cnt;
    for (int ai = 0; ai < na; ++ai) {
        const int pl = amb_list[ai];
        const int sp = sp0 + pl;
        const float Ap = A[p0 + pl];
        float bs = 3.4e38f; int bkk = 0x7fffffff;
#pragma unroll
        for (int j = 0; j < 4; ++j) {
            const int k = t + 256 * j;                // ascending k per thread
            float acc = 0.f;
            for (int d = 0; d < D; ++d)               // sequential-d FMA chain
                acc = __builtin_fmaf(x[(size_t)b * XSTRIDE + (size_t)d * HW + sp],
                                     e[d * K + k], acc);
            const float sc = __builtin_fmaf(-2.f, acc, Ap) + c2_lds[k];
            if (sc < bs || (sc == bs && k < bkk)) { bs = sc; bkk = k; }
        }
        rs[t] = bs; rk[t] = bkk;
        __syncthreads();
        for (int off = 128; off > 0; off >>= 1) {
            if (t < off) {
                const float so = rs[t + off]; const int ko = rk[t + off];
                if (so < rs[t] || (so == rs[t] && ko < rk[t])) { rs[t] = so; rk[t] = ko; }
            }
            __syncthreads();
        }
        const int kb = rk[0];
        if (t < 64) {
            const float xq = x[(size_t)b * XSTRIDE + (size_t)t * HW + sp];
            const float qv = eT[(size_t)kb * 64 + t];
            out[(size_t)b * XSTRIDE + (size_t)t * HW + sp] = xq + (qv - xq);
        }
        __syncthreads();
    }
}

extern "C" void kernel_launch(void* const* d_in, const int* in_sizes, int n_in,
                              void* d_out, int out_size, void* d_ws, size_t ws_size,
                              hipStream_t stream) {
    const float* x = (const float*)d_in[0];
    const float* e = (const float*)d_in[1];
    float* out = (float*)d_out;

    char* ws = (char*)d_ws;                          // 772 KB used
    unsigned short* ebf = (unsigned short*)ws;       // 256 KB B-fragments
    float* eT = (float*)(ws + 262144);               // 256 KB fp32 rows
    float* c2 = (float*)(ws + 524288);               // 4 KB
    float* A  = (float*)(ws + 528384);               // 256 KB norms

    vq_prep<<<324, 256, 0, stream>>>(e, x, ebf, eT, c2, A);
    vq_main<<<NPOS / 64, 256, 0, stream>>>(x, e, ebf, eT, c2, A, out);
}